// Round 11
// baseline (246.422 us; speedup 1.0000x reference)
//
#include <hip/hip_runtime.h>
#include <math.h>

// ---------------------------------------------------------------------------
// SharedAttentionProcessor: B=4, H=20, S=1024, C=1280, hd=64
// R20: QKV projection GEMM now writes THREE COMPACT buffers qb/kb/vb
// (region = nt/5 is block-uniform since 256-wide n-tiles never straddle the
// 1280/2560 boundaries) -- zero extra cost in the GEMM epilogue. stats1, vt
// and attn (stageK + Q prologue) read compact 2560B-stride rows again,
// reverting the R16 regression (interleaved 7680B-stride Q/K reads cost
// attn 61.4 -> 65.2us) while keeping the adain fold.
// R18/R19: GEMMs as counted-vmcnt pipelines (BK=32, 4 slots, vmcnt(8),
// one barrier/iter; neutral vs phased but cleaner -- kept).
// R17: div-free folded-affine attn prologue (coeffs from k_stats2).
// R16: adain fold removes qn/kn + adain pass. R15/R14: K/V LDS T2 swizzle.
// R13: counted vmcnt in attn. R10: cvt_pk casts.
// ---------------------------------------------------------------------------

typedef __bf16 bf16x8 __attribute__((ext_vector_type(8)));
typedef __bf16 bf16x2_t __attribute__((ext_vector_type(2)));
typedef float f32x4 __attribute__((ext_vector_type(4)));
typedef unsigned short u16x8 __attribute__((ext_vector_type(8)));

#define BDIM 256

__device__ inline unsigned short f2bf(float f) {
  return __builtin_bit_cast(unsigned short, (__bf16)f);
}
__device__ inline unsigned int pack_bf2(float lo, float hi) {
  bf16x2_t v;
  v[0] = (__bf16)lo;
  v[1] = (__bf16)hi;
  return __builtin_bit_cast(unsigned int, v);
}
__device__ inline float bf2f(unsigned short h) {
  return __uint_as_float(((unsigned int)h) << 16);
}

__device__ inline void gl_lds16(const unsigned short* g, unsigned short* l) {
  __builtin_amdgcn_global_load_lds(
      (const __attribute__((address_space(1))) unsigned int*)g,
      (__attribute__((address_space(3))) unsigned int*)l, 16, 0, 0);
}

// --------------------------- fused fp32 -> bf16 convert ---------------------
__global__ __launch_bounds__(BDIM) void k_convert_all(
    const float* __restrict__ X, const float* __restrict__ Wq,
    const float* __restrict__ Wk, const float* __restrict__ Wv,
    const float* __restrict__ Wo, unsigned short* __restrict__ Xbf,
    unsigned short* __restrict__ Wcat, unsigned short* __restrict__ Wobf) {
  const int idx = blockIdx.x * BDIM + threadIdx.x;
  const float* src;
  unsigned short* dst;
  int off;
  if (idx < 1310720) {
    src = X; dst = Xbf; off = idx;
  } else {
    const int r = idx - 1310720;
    const int which = r / 409600;
    off = r - which * 409600;
    src = (which == 0) ? Wq : (which == 1) ? Wk : (which == 2) ? Wv : Wo;
    dst = (which < 3) ? Wcat + (size_t)which * 1638400 : Wobf;
  }
  const float4 v = ((const float4*)src)[off];
  ushort4 o;
  o.x = f2bf(v.x); o.y = f2bf(v.y); o.z = f2bf(v.z); o.w = f2bf(v.w);
  ((ushort4*)dst)[off] = o;
}

// ---- bf16 GEMM 256x256, BK=32, 4-slot counted-vmcnt pipeline (QKV) ---------
// C[m][n] = sum_k A[m][k]*B[n][k]; writes compact qb/kb/vb (region = nt/5,
// block-uniform; per-buffer row stride 1280).
__global__ __launch_bounds__(512, 1) void k_gemm_bf16(
    const unsigned short* __restrict__ A, const unsigned short* __restrict__ B,
    unsigned short* __restrict__ qb, unsigned short* __restrict__ kb,
    unsigned short* __restrict__ vb, int M, int N, int K) {
  __shared__ unsigned short lds[4][2][256 * 32];  // [slot][A|B][256 rows x 32]

  const int bid = blockIdx.x;
  const int swz = (bid & 7) * 30 + (bid >> 3);  // XCD-bijective (240%8==0)
  const int mt = swz & 15, nt = swz >> 4;
  const int mBase = mt * 256, nBase = nt * 256;
  const int r3 = nt / 5;                        // 0=Q, 1=K, 2=V
  unsigned short* Cb = (r3 == 0) ? qb : (r3 == 1) ? kb : vb;
  const int nOff = nBase - r3 * 1280;

  const int t = threadIdx.x;
  const int w = t >> 6, lane = t & 63, quad = lane >> 4, l16 = lane & 15;
  const int wrow = w & 1, wcol = w >> 1;        // 2 M-waves x 4 N-waves
  const int NTILES = K >> 5;                    // 40

  f32x4 acc[8][4];
#pragma unroll
  for (int i = 0; i < 8; ++i)
#pragma unroll
    for (int j = 0; j < 4; ++j) acc[i][j] = (f32x4){0.f, 0.f, 0.f, 0.f};

  const int srow = t >> 2;                          // 0..127
  const int sgl = ((t & 3) ^ ((t >> 3) & 3)) * 8;   // T2 pre-swizzled source

  auto stage = [&](int s, int kt) {                 // 4 loads/thread
#pragma unroll
    for (int j = 0; j < 2; ++j) {
      const int row = j * 128 + srow;
      gl_lds16(A + (size_t)(mBase + row) * K + kt * 32 + sgl,
               &lds[s][0][(j * 512 + t) * 8]);
    }
#pragma unroll
    for (int j = 0; j < 2; ++j) {
      const int row = j * 128 + srow;
      gl_lds16(B + (size_t)(nBase + row) * K + kt * 32 + sgl,
               &lds[s][1][(j * 512 + t) * 8]);
    }
  };

  stage(0, 0);
  stage(1, 1);

  const int arow0 = (wrow * 128 + l16) * 32;
  const int brow0 = (wcol * 64 + l16) * 32;
  const int gsw = (quad ^ ((l16 >> 1) & 3)) * 8;    // T2 read-side XOR

  for (int kt = 0; kt < NTILES; ++kt) {
    const int s = kt & 3;
    if (kt + 2 < NTILES) {
      stage((kt + 2) & 3, kt + 2);
      asm volatile("s_waitcnt vmcnt(8)" ::: "memory");  // tile kt resident
    } else if (kt + 1 < NTILES) {
      asm volatile("s_waitcnt vmcnt(4)" ::: "memory");
    } else {
      asm volatile("s_waitcnt vmcnt(0)" ::: "memory");
    }
    __builtin_amdgcn_s_barrier();  // one barrier/iter: RAW + WAR

    const unsigned short* As = &lds[s][0][0];
    const unsigned short* Bs = &lds[s][1][0];
    bf16x8 af[8], bq[4];
#pragma unroll
    for (int mi = 0; mi < 8; ++mi)
      af[mi] = *(const bf16x8*)(As + arow0 + mi * 512 + gsw);
#pragma unroll
    for (int ni = 0; ni < 4; ++ni)
      bq[ni] = *(const bf16x8*)(Bs + brow0 + ni * 512 + gsw);
    __builtin_amdgcn_s_setprio(1);
#pragma unroll
    for (int mi = 0; mi < 8; ++mi)
#pragma unroll
      for (int ni = 0; ni < 4; ++ni)
        acc[mi][ni] = __builtin_amdgcn_mfma_f32_16x16x32_bf16(
            af[mi], bq[ni], acc[mi][ni], 0, 0, 0);
    __builtin_amdgcn_s_setprio(0);
  }

#pragma unroll
  for (int mi = 0; mi < 8; ++mi)
#pragma unroll
    for (int r = 0; r < 4; ++r) {
      const int row = mBase + wrow * 128 + mi * 16 + quad * 4 + r;
#pragma unroll
      for (int ni = 0; ni < 4; ++ni)
        Cb[(size_t)row * 1280 + nOff + wcol * 64 + ni * 16 + l16] =
            f2bf(acc[mi][ni][r]);
    }
}

// ---- bf16 GEMM 128x128, BK=32, 4-slot counted-vmcnt (out proj) -------------
__global__ __launch_bounds__(BDIM, 2) void k_gemm_out(
    const unsigned short* __restrict__ A, const unsigned short* __restrict__ B,
    float* __restrict__ Cf, const float* __restrict__ bias, int M, int N,
    int K) {
  __shared__ unsigned short lds[4][2][128 * 32];  // [slot][A|B][128 rows x 32]

  const int bid = blockIdx.x;
  const int swz = (bid & 7) * 40 + (bid >> 3);  // 320 % 8 == 0, bijective
  const int mt = swz & 31, nt = swz >> 5;       // 32 x 10
  const int mBase = mt * 128, nBase = nt * 128;

  const int t = threadIdx.x;
  const int w = t >> 6, lane = t & 63, quad = lane >> 4, l16 = lane & 15;
  const int wrow = w & 1, wcol = w >> 1;        // 2x2 waves, wave-tile 64x64
  const int NTILES = K >> 5;                    // 40

  f32x4 acc[4][4];
#pragma unroll
  for (int i = 0; i < 4; ++i)
#pragma unroll
    for (int j = 0; j < 4; ++j) acc[i][j] = (f32x4){0.f, 0.f, 0.f, 0.f};

  const int srow = t >> 2;                          // 0..63
  const int sgl = ((t & 3) ^ ((t >> 3) & 3)) * 8;

  auto stage = [&](int s, int kt) {                 // 4 loads/thread
#pragma unroll
    for (int j = 0; j < 2; ++j) {
      const int row = j * 64 + srow;
      gl_lds16(A + (size_t)(mBase + row) * K + kt * 32 + sgl,
               &lds[s][0][(j * 256 + t) * 8]);
    }
#pragma unroll
    for (int j = 0; j < 2; ++j) {
      const int row = j * 64 + srow;
      gl_lds16(B + (size_t)(nBase + row) * K + kt * 32 + sgl,
               &lds[s][1][(j * 256 + t) * 8]);
    }
  };

  stage(0, 0);
  stage(1, 1);

  const int arow0 = (wrow * 64 + l16) * 32;
  const int brow0 = (wcol * 64 + l16) * 32;
  const int gsw = (quad ^ ((l16 >> 1) & 3)) * 8;

  for (int kt = 0; kt < NTILES; ++kt) {
    const int s = kt & 3;
    if (kt + 2 < NTILES) {
      stage((kt + 2) & 3, kt + 2);
      asm volatile("s_waitcnt vmcnt(8)" ::: "memory");
    } else if (kt + 1 < NTILES) {
      asm volatile("s_waitcnt vmcnt(4)" ::: "memory");
    } else {
      asm volatile("s_waitcnt vmcnt(0)" ::: "memory");
    }
    __builtin_amdgcn_s_barrier();

    const unsigned short* As = &lds[s][0][0];
    const unsigned short* Bs = &lds[s][1][0];
    bf16x8 af[4], bq[4];
#pragma unroll
    for (int mi = 0; mi < 4; ++mi)
      af[mi] = *(const bf16x8*)(As + arow0 + mi * 512 + gsw);
#pragma unroll
    for (int ni = 0; ni < 4; ++ni)
      bq[ni] = *(const bf16x8*)(Bs + brow0 + ni * 512 + gsw);
    __builtin_amdgcn_s_setprio(1);
#pragma unroll
    for (int mi = 0; mi < 4; ++mi)
#pragma unroll
      for (int ni = 0; ni < 4; ++ni)
        acc[mi][ni] = __builtin_amdgcn_mfma_f32_16x16x32_bf16(
            af[mi], bq[ni], acc[mi][ni], 0, 0, 0);
    __builtin_amdgcn_s_setprio(0);
  }

#pragma unroll
  for (int mi = 0; mi < 4; ++mi)
#pragma unroll
    for (int r = 0; r < 4; ++r) {
      const int row = mBase + wrow * 64 + mi * 16 + quad * 4 + r;
#pragma unroll
      for (int ni = 0; ni < 4; ++ni) {
        const int col = nBase + wcol * 64 + ni * 16 + l16;
        Cf[(size_t)row * N + col] = acc[mi][ni][r] + bias[col];
      }
    }
}

// --------------------------- adain stats (two-stage) ------------------------
// reads compact qb/kb (row stride 1280)
__global__ __launch_bounds__(320) void k_stats1(
    const unsigned short* __restrict__ qb, const unsigned short* __restrict__ kb,
    float* __restrict__ psum, float* __restrict__ psq) {
  const int z = blockIdx.y, which = z >> 2, b = z & 3;
  const unsigned short* src = (which == 0) ? qb : kb;
  const int c = threadIdx.x * 4;
  const size_t base = (size_t)(b * 1024 + blockIdx.x * 32) * 1280 + c;
  float4 s = {0.f, 0.f, 0.f, 0.f}, s2 = {0.f, 0.f, 0.f, 0.f};
#pragma unroll 8
  for (int i = 0; i < 32; ++i) {
    const ushort4 xv = *(const ushort4*)(src + base + (size_t)i * 1280);
    const float x0 = bf2f(xv.x), x1 = bf2f(xv.y), x2 = bf2f(xv.z),
                x3 = bf2f(xv.w);
    s.x += x0; s.y += x1; s.z += x2; s.w += x3;
    s2.x = fmaf(x0, x0, s2.x); s2.y = fmaf(x1, x1, s2.y);
    s2.z = fmaf(x2, x2, s2.z); s2.w = fmaf(x3, x3, s2.w);
  }
  const size_t o = ((size_t)z * 32 + blockIdx.x) * 1280 + c;
  *(float4*)(psum + o) = s;
  *(float4*)(psq + o) = s2;
}

// stats2: reduce partials for ALL 4 batches, emit folded affine coefficients.
// fst layout [(coef*4 + b)*1280 + c]: coef 0=gQ, 1=oQ, 2=gK*S2, 3=oK.
__global__ __launch_bounds__(BDIM) void k_stats2(
    const float* __restrict__ psum, const float* __restrict__ psq,
    float* __restrict__ fst) {
  const int which = blockIdx.y;  // 0=Q, 1=K
  const int c = blockIdx.x * 256 + threadIdx.x;
  float m[4], sd[4];
#pragma unroll
  for (int b = 0; b < 4; ++b) {
    const int z = which * 4 + b;
    float s = 0.f, s2 = 0.f;
#pragma unroll
    for (int j = 0; j < 32; ++j) {
      s += psum[((size_t)z * 32 + j) * 1280 + c];
      s2 += psq[((size_t)z * 32 + j) * 1280 + c];
    }
    const float mean = s * (1.0f / 1024.0f);
    const float var = (s2 - 1024.0f * mean * mean) * (1.0f / 1023.0f);
    m[b] = mean;
    sd[b] = sqrtf(var + 1e-5f);
  }
  const float S2 = 0.125f * 1.44269504088896341f;
#pragma unroll
  for (int b = 0; b < 4; ++b) {
    const int bs = (b < 2) ? 0 : 2;
    const float g = sd[bs] / sd[b];
    const float o = m[bs] - m[b] * g;
    if (which == 0) {
      fst[(0 * 4 + b) * 1280 + c] = g;
      fst[(1 * 4 + b) * 1280 + c] = o;
    } else {
      fst[(2 * 4 + b) * 1280 + c] = g * S2;
      fst[(3 * 4 + b) * 1280 + c] = o;
    }
  }
}

// --------------------------- V transpose only -------------------------------
// reads compact vb (row stride 1280)
__global__ __launch_bounds__(BDIM) void k_vt(
    const unsigned short* __restrict__ vb, unsigned short* __restrict__ vt) {
  __shared__ unsigned short tile[64][65];
  const int tb = blockIdx.x;            // [0,1280)
  const int b = tb / 320;
  const int r2 = tb - b * 320;
  const int c0 = (r2 / 16) * 64;
  const int s0 = (r2 & 15) * 64;
  const int t = threadIdx.x;
  const int r = t >> 2, seg = (t & 3) * 16;
  const size_t goff = ((size_t)(b * 1024 + s0 + r)) * 1280 + c0 + seg;
  const u16x8 va = *(const u16x8*)(vb + goff);
  const u16x8 vv = *(const u16x8*)(vb + goff + 8);
#pragma unroll
  for (int j = 0; j < 8; j++) {
    tile[r][seg + j] = va[j];
    tile[r][seg + 8 + j] = vv[j];
  }
  __syncthreads();
  u16x8 o0, o1;
#pragma unroll
  for (int j = 0; j < 8; j++) {
    o0[j] = tile[seg + j][r];
    o1[j] = tile[seg + 8 + j][r];
  }
  const size_t ooff = ((size_t)(b * 1280 + c0 + r)) * 1024 + s0 + seg;
  *(u16x8*)(vt + ooff) = o0;
  *(u16x8*)(vt + ooff + 8) = o1;
}

// --------------------------- flash attention --------------------------------
// Q/K from compact qb/kb; adain+K-fold via precomputed affine coefficients:
// qn = fma(q,gQ,oQ); rq += qn*oK; a = qn*gKS2; bias = (style?1:0)+red(rq)*S2.
__global__ __launch_bounds__(BDIM, 4) void k_attn(
    const unsigned short* __restrict__ qb, const unsigned short* __restrict__ kb,
    const float* __restrict__ fst, const unsigned short* __restrict__ vt,
    unsigned short* __restrict__ Op0, unsigned short* __restrict__ Op1,
    float* __restrict__ Lpart) {
  const int S = 1024;
  const int L = blockIdx.x + 8 * (blockIdx.y + 20 * blockIdx.z);
  const int qt = (L >> 3) & 7;
  const int hz = (L & 7) + ((L >> 6) << 3);  // 0..239
  const int h = hz % 20;
  const int zs = hz / 20;
  int b, chunk;
  if (zs < 2)      { b = 0; chunk = zs; }
  else if (zs < 6) { b = 1; chunk = zs - 2; }
  else if (zs < 8) { b = 2; chunk = zs - 6; }
  else             { b = 3; chunk = zs - 8; }
  const int ktBeg = chunk * 8;
  const int t = threadIdx.x, w = t >> 6, lane = t & 63;
  const int quad = lane >> 4, l16 = lane & 15;
  const int bstyle = (b < 2) ? 0 : 2;
  const int qrow = qt * 128 + w * 32;
  const bool style = (ktBeg >= 16);

  __shared__ unsigned short Ks[2][2][64 * 32];  // [buf][dim-half] 16 KB
  __shared__ unsigned short Vs[2][64 * 32];     // [key-half]       8 KB
  __shared__ unsigned short Plds[4][32][64];    // XOR-swizzled    16 KB

  const float S2 = 0.125f * 1.44269504088896341f;

  // ---- prologue: folded affine on Q, bias scalar (no divisions) ----
  bf16x8 aq[2][2];
  float biasv[2];
  {
    const int bk = style ? bstyle : b;  // K-coef batch (style: {S2, 0})
    float rq[2] = {0.f, 0.f};
#pragma unroll
    for (int hf = 0; hf < 2; ++hf) {
      const int cc = h * 64 + quad * 8 + hf * 32;
      float gq[8], oq[8], gs[8], ok[8];
      *(float4*)(gq)     = *(const float4*)(fst + (0 * 4 + b) * 1280 + cc);
      *(float4*)(gq + 4) = *(const float4*)(fst + (0 * 4 + b) * 1280 + cc + 4);
      *(float4*)(oq)     = *(const float4*)(fst + (1 * 4 + b) * 1280 + cc);
      *(float4*)(oq + 4) = *(const float4*)(fst + (1 * 4 + b) * 1280 + cc + 4);
      *(float4*)(gs)     = *(const float4*)(fst + (2 * 4 + bk) * 1280 + cc);
      *(float4*)(gs + 4) = *(const float4*)(fst + (2 * 4 + bk) * 1280 + cc + 4);
      *(float4*)(ok)     = *(const float4*)(fst + (3 * 4 + bk) * 1280 + cc);
      *(float4*)(ok + 4) = *(const float4*)(fst + (3 * 4 + bk) * 1280 + cc + 4);
#pragma unroll
      for (int g = 0; g < 2; ++g) {
        const size_t qoff =
            ((size_t)(b * S + qrow + g * 16 + l16)) * 1280 + cc;
        const bf16x8 qv = *(const bf16x8*)(qb + qoff);
        bf16x8 av;
#pragma unroll
        for (int j = 0; j < 8; ++j) {
          const float qn = fmaf((float)qv[j], gq[j], oq[j]);
          rq[g] = fmaf(qn, ok[j], rq[g]);
          av[j] = (__bf16)(qn * gs[j]);
        }
        aq[g][hf] = av;
      }
    }
    const float shift = style ? 1.0f : 0.0f;
#pragma unroll
    for (int g = 0; g < 2; ++g) {
      float r = rq[g] * S2;
      r += __shfl_xor(r, 16, 64);  // sum over the 4 quads of one query row
      r += __shfl_xor(r, 32, 64);
      biasv[g] = shift + r;        // style: rq == 0 exactly -> bias = 1
    }
  }

  bf16x8 ones;
#pragma unroll
  for (int i = 0; i < 8; ++i) ones[i] = (__bf16)1.0f;

  f32x4 o[2][4], lsum[2];
#pragma unroll
  for (int g = 0; g < 2; ++g) {
    lsum[g] = (f32x4){0.f, 0.f, 0.f, 0.f};
#pragma unroll
    for (int i = 0; i < 4; i++) o[g][i] = (f32x4){0.f, 0.f, 0.f, 0.f};
  }

  const int krow = t >> 2;
  const int kseg = ((t & 3) ^ ((t >> 3) & 3)) * 8;  // T2 pre-swizzled source
  const int sw = l16 & 14;
  const int qsw = (quad ^ ((l16 >> 1) & 3)) * 8;    // T2 read-side XOR

  auto stageK = [&](int buf, int kt) {
    const int bs = (kt < 16) ? b : bstyle;
    const int sk = (kt & 15) * 64;
    const unsigned short* kg =
        kb + (size_t)(bs * S + sk + krow) * 1280 + h * 64 + kseg;
    gl_lds16(kg, Ks[buf][0] + t * 8);
    gl_lds16(kg + 32, Ks[buf][1] + t * 8);
  };
  auto stageV = [&](int kt) {
    const int bs = (kt < 16) ? b : bstyle;
    const int sk = (kt & 15) * 64;
    const unsigned short* vg =
        vt + (size_t)(bs * 1280 + h * 64 + krow) * S + sk + kseg;
    gl_lds16(vg, Vs[0] + t * 8);
    gl_lds16(vg + 32, Vs[1] + t * 8);
  };

  stageK(0, ktBeg);

  for (int i = 0; i < 8; ++i) {
    const int kt = ktBeg + i;
    const int buf = i & 1;
    asm volatile("s_waitcnt vmcnt(0)" ::: "memory");
    __builtin_amdgcn_s_barrier();
    stageV(kt);
    if (i + 1 < 8) stageK(buf ^ 1, kt + 1);

    // S^T: D[m=key (nt*16+quad*4+r)][n=query l16]
    f32x4 z2[2][4];
#pragma unroll
    for (int nt = 0; nt < 4; ++nt) {
      const bf16x8 bk0 =
          *(const bf16x8*)(Ks[buf][0] + (nt * 16 + l16) * 32 + qsw);
      const bf16x8 bk1 =
          *(const bf16x8*)(Ks[buf][1] + (nt * 16 + l16) * 32 + qsw);
#pragma unroll
      for (int g = 0; g < 2; ++g) {
        f32x4 zz = (f32x4){0.f, 0.f, 0.f, 0.f};
        zz = __builtin_amdgcn_mfma_f32_16x16x32_bf16(bk0, aq[g][0], zz, 0, 0, 0);
        zz = __builtin_amdgcn_mfma_f32_16x16x32_bf16(bk1, aq[g][1], zz, 0, 0, 0);
        z2[g][nt] = zz;
      }
    }

    // exp2 (bias folded), pack -> swizzled b64 write
#pragma unroll
    for (int g = 0; g < 2; ++g) {
      const float bg = biasv[g];
#pragma unroll
      for (int nt = 0; nt < 4; ++nt) {
        const float e0 = exp2f(z2[g][nt][0] + bg);
        const float e1 = exp2f(z2[g][nt][1] + bg);
        const float e2 = exp2f(z2[g][nt][2] + bg);
        const float e3 = exp2f(z2[g][nt][3] + bg);
        uint2 pk;
        pk.x = pack_bf2(e0, e1);
        pk.y = pack_bf2(e2, e3);
        const int phys = (nt * 4 + quad) ^ sw;
        *(uint2*)(&Plds[w][g * 16 + l16][phys * 4]) = pk;
      }
    }

    if (i + 1 < 8)
      asm volatile("s_waitcnt vmcnt(2)" ::: "memory");
    else
      asm volatile("s_waitcnt vmcnt(0)" ::: "memory");
    __builtin_amdgcn_s_barrier();

    // lsum += P*1 ; O += P*V^T
#pragma unroll
    for (int g = 0; g < 2; ++g) {
      const int a0 = (2 * quad) ^ sw;
      const int a1 = (2 * quad + 8) ^ sw;
      const bf16x8 pa0 = *(const bf16x8*)(&Plds[w][g * 16 + l16][a0 * 4]);
      const bf16x8 pa1 = *(const bf16x8*)(&Plds[w][g * 16 + l16][a1 * 4]);
      lsum[g] = __builtin_amdgcn_mfma_f32_16x16x32_bf16(pa0, ones, lsum[g], 0, 0, 0);
      lsum[g] = __builtin_amdgcn_mfma_f32_16x16x32_bf16(pa1, ones, lsum[g], 0, 0, 0);
#pragma unroll
      for (int dt = 0; dt < 4; ++dt) {
        const bf16x8 vb0 =
            *(const bf16x8*)(Vs[0] + (dt * 16 + l16) * 32 + qsw);
        const bf16x8 vb1 =
            *(const bf16x8*)(Vs[1] + (dt * 16 + l16) * 32 + qsw);
        o[g][dt] =
            __builtin_amdgcn_mfma_f32_16x16x32_bf16(pa0, vb0, o[g][dt], 0, 0, 0);
        o[g][dt] =
            __builtin_amdgcn_mfma_f32_16x16x32_bf16(pa1, vb1, o[g][dt], 0, 0, 0);
      }
    }
  }

  if (l16 == 0) {
#pragma unroll
    for (int g = 0; g < 2; ++g)
#pragma unroll
      for (int r = 0; r < 4; ++r)
        Lpart[((size_t)zs * 20 + h) * 1024 + qrow + g * 16 + quad * 4 + r] =
            lsum[g][r];
  }

  unsigned short* Op = (zs < 4) ? Op0 + (size_t)zs * 1310720
                                : Op1 + (size_t)(zs - 4) * 1310720;
#pragma unroll
  for (int g = 0; g < 2; ++g)
#pragma unroll
    for (int dt = 0; dt < 4; ++dt)
#pragma unroll
      for (int r = 0; r < 4; ++r)
        Op[(size_t)(qrow + g * 16 + quad * 4 + r) * 1280 + h * 64 + dt * 16 +
           l16] = f2bf(o[g][dt][r]);
}

// --------------------------- combine slice partials -------------------------
__global__ __launch_bounds__(BDIM) void k_combine(
    const unsigned short* __restrict__ Op0, const unsigned short* __restrict__ Op1,
    const float* __restrict__ Lpart, unsigned short* __restrict__ attnb) {
  const int idx = blockIdx.x * BDIM + threadIdx.x;  // [0, 655360)
  const int row = idx / 160;
  const int c = (idx - row * 160) * 8;
  const int b = row >> 10, q = row & 1023, h = c >> 6;
  const int zb = (b >> 1) * 6 + (b & 1) * 2;  // 0,2,6,8
  const int ns = 2 + (b & 1) * 2;             // 2 or 4 slices
  float L = 0.f;
  float acc[8] = {0.f, 0.f, 0.f, 0.f, 0.f, 0.f, 0.f, 0.f};
  for (int s = 0; s < ns; ++s) {
    const int z = zb + s;
    const unsigned short* base = (z < 4)
        ? Op0 + (size_t)z * 1310720
        : Op1 + (size_t)(z - 4) * 1310720;
    L += Lpart[((size_t)z * 20 + h) * 1024 + q];
    const u16x8 v = *(const u16x8*)(base + (size_t)q * 1280 + c);
#pragma unroll
    for (int j = 0; j < 8; ++j) acc[j] += bf2f(v[j]);
  }
  const float rl = 1.0f / L;
  u16x8 o8;
#pragma unroll
  for (int j = 0; j < 8; ++j) o8[j] = f2bf(acc[j] * rl);
  *(u16x8*)(attnb + (size_t)row * 1280 + c) = o8;
}

// ---------------------------------------------------------------------------
extern "C" void kernel_launch(void* const* d_in, const int* in_sizes, int n_in,
                              void* d_out, int out_size, void* d_ws,
                              size_t ws_size, hipStream_t stream) {
  const float* X = (const float*)d_in[0];
  const float* Wq = (const float*)d_in[1];
  const float* Wk = (const float*)d_in[2];
  const float* Wv = (const float*)d_in[3];
  const float* Wo = (const float*)d_in[4];
  const float* bo = (const float*)d_in[5];
  float* out = (float*)d_out;

  char* ws = (char*)d_ws;
  size_t off = 0;
  auto alloc = [&](size_t bytes) {
    char* p = ws + off;
    off += (bytes + 255) & ~(size_t)255;
    return p;
  };
  unsigned short* Wcat = (unsigned short*)alloc(3840ull * 1280 * 2);
  unsigned short* Xbf = (unsigned short*)alloc(4096ull * 1280 * 2);
  unsigned short* qbb = (unsigned short*)alloc(4096ull * 1280 * 2);
  unsigned short* kbb = (unsigned short*)alloc(4096ull * 1280 * 2);
  unsigned short* vbb = (unsigned short*)alloc(4096ull * 1280 * 2);
  unsigned short* Wobf = (unsigned short*)alloc(1280ull * 1280 * 2);
  float* fstats = (float*)alloc(4ull * 4 * 1280 * 4);
  unsigned short* qnb = (unsigned short*)alloc(4096ull * 1280 * 2);
  unsigned short* knb = (unsigned short*)alloc(4096ull * 1280 * 2);
  unsigned short* vtb = (unsigned short*)alloc(4096ull * 1280 * 2);
  unsigned short* attnb = (unsigned short*)alloc(4096ull * 1280 * 2);
  (void)knb;  // Op1 spans qnb+knb (contiguous, 8 slices)

  unsigned short* Op0 = Xbf;   // slices 0-3 (Xbf dead after gemm_bf16)
  unsigned short* Op1 = qnb;   // slices 4-11 (qnb+knb contiguous scratch)
  float* Lpart = (float*)Wcat;                        // 12 x 20 x 1024 fp32
  float* psum = (float*)attnb;                        // 8 x 32 x 1280 fp32
  float* psq = (float*)(attnb + 4096ull * 1280 / 2);  // second half

  k_convert_all<<<11520, BDIM, 0, stream>>>(X, Wq, Wk, Wv, Wo, Xbf, Wcat, Wobf);
  k_gemm_bf16<<<240, 512, 0, stream>>>(Xbf, Wcat, qbb, kbb, vbb, 4096, 3840,
                                       1280);
  k_stats1<<<dim3(32, 8), 320, 0, stream>>>(qbb, kbb, psum, psq);
  k_stats2<<<dim3(5, 2), BDIM, 0, stream>>>(psum, psq, fstats);
  k_vt<<<1280, BDIM, 0, stream>>>(vbb, vtb);
  k_attn<<<dim3(8, 20, 12), BDIM, 0, stream>>>(qbb, kbb, fstats, vtb, Op0, Op1,
                                               Lpart);
  k_combine<<<2560, BDIM, 0, stream>>>(Op0, Op1, Lpart, attnb);
  k_gemm_out<<<320, BDIM, 0, stream>>>(attnb, Wobf, out, bo, 4096, 1280, 1280);
}

// Round 12
// 239.254 us; speedup vs baseline: 1.0300x; 1.0300x over previous
//
#include <hip/hip_runtime.h>
#include <math.h>

// ---------------------------------------------------------------------------
// SharedAttentionProcessor: B=4, H=20, S=1024, C=1280, hd=64
// R21: attn slicing coarsened 8->16 K-tiles/block: grid (8,20,6)=960 uniform
// blocks (single scheduling round, was 1920 over 2 partial rounds). Style
// batches b0/b2 (zs 0/3) own all 16 self tiles and normalize+write attnb
// DIRECTLY (no Opart/Lpart/combine for them -- the concat-with-self x3
// cancels, same algebra the old kernel used). b1/b3 split self/style into 2
// blocks -> only 4 Opart slices (10.5 MB in dead Xbf); k_combine handles
// only b1/b3 rows (1280 blocks, 1/3 traffic). Each block still has ONE aq
// set + ONE bias. stageK(0) issued BEFORE the prologue (K HBM latency hides
// under prologue fma chain). Prologue count halved.
// R20: compact qb/kb/vb from QKV GEMM (neutral, kept). R18/R19: GEMMs as
// counted-vmcnt pipelines. R17: div-free folded-affine prologue.
// R16: adain fold. R15/R14: K/V LDS T2 swizzle. R10: cvt_pk casts.
// ---------------------------------------------------------------------------

typedef __bf16 bf16x8 __attribute__((ext_vector_type(8)));
typedef __bf16 bf16x2_t __attribute__((ext_vector_type(2)));
typedef float f32x4 __attribute__((ext_vector_type(4)));
typedef unsigned short u16x8 __attribute__((ext_vector_type(8)));

#define BDIM 256

__device__ inline unsigned short f2bf(float f) {
  return __builtin_bit_cast(unsigned short, (__bf16)f);
}
__device__ inline unsigned int pack_bf2(float lo, float hi) {
  bf16x2_t v;
  v[0] = (__bf16)lo;
  v[1] = (__bf16)hi;
  return __builtin_bit_cast(unsigned int, v);
}
__device__ inline float bf2f(unsigned short h) {
  return __uint_as_float(((unsigned int)h) << 16);
}

__device__ inline void gl_lds16(const unsigned short* g, unsigned short* l) {
  __builtin_amdgcn_global_load_lds(
      (const __attribute__((address_space(1))) unsigned int*)g,
      (__attribute__((address_space(3))) unsigned int*)l, 16, 0, 0);
}

// --------------------------- fused fp32 -> bf16 convert ---------------------
__global__ __launch_bounds__(BDIM) void k_convert_all(
    const float* __restrict__ X, const float* __restrict__ Wq,
    const float* __restrict__ Wk, const float* __restrict__ Wv,
    const float* __restrict__ Wo, unsigned short* __restrict__ Xbf,
    unsigned short* __restrict__ Wcat, unsigned short* __restrict__ Wobf) {
  const int idx = blockIdx.x * BDIM + threadIdx.x;
  const float* src;
  unsigned short* dst;
  int off;
  if (idx < 1310720) {
    src = X; dst = Xbf; off = idx;
  } else {
    const int r = idx - 1310720;
    const int which = r / 409600;
    off = r - which * 409600;
    src = (which == 0) ? Wq : (which == 1) ? Wk : (which == 2) ? Wv : Wo;
    dst = (which < 3) ? Wcat + (size_t)which * 1638400 : Wobf;
  }
  const float4 v = ((const float4*)src)[off];
  ushort4 o;
  o.x = f2bf(v.x); o.y = f2bf(v.y); o.z = f2bf(v.z); o.w = f2bf(v.w);
  ((ushort4*)dst)[off] = o;
}

// ---- bf16 GEMM 256x256, BK=32, 4-slot counted-vmcnt pipeline (QKV) ---------
__global__ __launch_bounds__(512, 1) void k_gemm_bf16(
    const unsigned short* __restrict__ A, const unsigned short* __restrict__ B,
    unsigned short* __restrict__ qb, unsigned short* __restrict__ kb,
    unsigned short* __restrict__ vb, int M, int N, int K) {
  __shared__ unsigned short lds[4][2][256 * 32];  // [slot][A|B][256 rows x 32]

  const int bid = blockIdx.x;
  const int swz = (bid & 7) * 30 + (bid >> 3);  // XCD-bijective (240%8==0)
  const int mt = swz & 15, nt = swz >> 4;
  const int mBase = mt * 256, nBase = nt * 256;
  const int r3 = nt / 5;                        // 0=Q, 1=K, 2=V
  unsigned short* Cb = (r3 == 0) ? qb : (r3 == 1) ? kb : vb;
  const int nOff = nBase - r3 * 1280;

  const int t = threadIdx.x;
  const int w = t >> 6, lane = t & 63, quad = lane >> 4, l16 = lane & 15;
  const int wrow = w & 1, wcol = w >> 1;        // 2 M-waves x 4 N-waves
  const int NTILES = K >> 5;                    // 40

  f32x4 acc[8][4];
#pragma unroll
  for (int i = 0; i < 8; ++i)
#pragma unroll
    for (int j = 0; j < 4; ++j) acc[i][j] = (f32x4){0.f, 0.f, 0.f, 0.f};

  const int srow = t >> 2;                          // 0..127
  const int sgl = ((t & 3) ^ ((t >> 3) & 3)) * 8;   // T2 pre-swizzled source

  auto stage = [&](int s, int kt) {                 // 4 loads/thread
#pragma unroll
    for (int j = 0; j < 2; ++j) {
      const int row = j * 128 + srow;
      gl_lds16(A + (size_t)(mBase + row) * K + kt * 32 + sgl,
               &lds[s][0][(j * 512 + t) * 8]);
    }
#pragma unroll
    for (int j = 0; j < 2; ++j) {
      const int row = j * 128 + srow;
      gl_lds16(B + (size_t)(nBase + row) * K + kt * 32 + sgl,
               &lds[s][1][(j * 512 + t) * 8]);
    }
  };

  stage(0, 0);
  stage(1, 1);

  const int arow0 = (wrow * 128 + l16) * 32;
  const int brow0 = (wcol * 64 + l16) * 32;
  const int gsw = (quad ^ ((l16 >> 1) & 3)) * 8;    // T2 read-side XOR

  for (int kt = 0; kt < NTILES; ++kt) {
    const int s = kt & 3;
    if (kt + 2 < NTILES) {
      stage((kt + 2) & 3, kt + 2);
      asm volatile("s_waitcnt vmcnt(8)" ::: "memory");  // tile kt resident
    } else if (kt + 1 < NTILES) {
      asm volatile("s_waitcnt vmcnt(4)" ::: "memory");
    } else {
      asm volatile("s_waitcnt vmcnt(0)" ::: "memory");
    }
    __builtin_amdgcn_s_barrier();  // one barrier/iter: RAW + WAR

    const unsigned short* As = &lds[s][0][0];
    const unsigned short* Bs = &lds[s][1][0];
    bf16x8 af[8], bq[4];
#pragma unroll
    for (int mi = 0; mi < 8; ++mi)
      af[mi] = *(const bf16x8*)(As + arow0 + mi * 512 + gsw);
#pragma unroll
    for (int ni = 0; ni < 4; ++ni)
      bq[ni] = *(const bf16x8*)(Bs + brow0 + ni * 512 + gsw);
    __builtin_amdgcn_s_setprio(1);
#pragma unroll
    for (int mi = 0; mi < 8; ++mi)
#pragma unroll
      for (int ni = 0; ni < 4; ++ni)
        acc[mi][ni] = __builtin_amdgcn_mfma_f32_16x16x32_bf16(
            af[mi], bq[ni], acc[mi][ni], 0, 0, 0);
    __builtin_amdgcn_s_setprio(0);
  }

#pragma unroll
  for (int mi = 0; mi < 8; ++mi)
#pragma unroll
    for (int r = 0; r < 4; ++r) {
      const int row = mBase + wrow * 128 + mi * 16 + quad * 4 + r;
#pragma unroll
      for (int ni = 0; ni < 4; ++ni)
        Cb[(size_t)row * 1280 + nOff + wcol * 64 + ni * 16 + l16] =
            f2bf(acc[mi][ni][r]);
    }
}

// ---- bf16 GEMM 128x128, BK=32, 4-slot counted-vmcnt (out proj) -------------
__global__ __launch_bounds__(BDIM, 2) void k_gemm_out(
    const unsigned short* __restrict__ A, const unsigned short* __restrict__ B,
    float* __restrict__ Cf, const float* __restrict__ bias, int M, int N,
    int K) {
  __shared__ unsigned short lds[4][2][128 * 32];  // [slot][A|B][128 rows x 32]

  const int bid = blockIdx.x;
  const int swz = (bid & 7) * 40 + (bid >> 3);  // 320 % 8 == 0, bijective
  const int mt = swz & 31, nt = swz >> 5;       // 32 x 10
  const int mBase = mt * 128, nBase = nt * 128;

  const int t = threadIdx.x;
  const int w = t >> 6, lane = t & 63, quad = lane >> 4, l16 = lane & 15;
  const int wrow = w & 1, wcol = w >> 1;        // 2x2 waves, wave-tile 64x64
  const int NTILES = K >> 5;                    // 40

  f32x4 acc[4][4];
#pragma unroll
  for (int i = 0; i < 4; ++i)
#pragma unroll
    for (int j = 0; j < 4; ++j) acc[i][j] = (f32x4){0.f, 0.f, 0.f, 0.f};

  const int srow = t >> 2;                          // 0..63
  const int sgl = ((t & 3) ^ ((t >> 3) & 3)) * 8;

  auto stage = [&](int s, int kt) {                 // 4 loads/thread
#pragma unroll
    for (int j = 0; j < 2; ++j) {
      const int row = j * 64 + srow;
      gl_lds16(A + (size_t)(mBase + row) * K + kt * 32 + sgl,
               &lds[s][0][(j * 256 + t) * 8]);
    }
#pragma unroll
    for (int j = 0; j < 2; ++j) {
      const int row = j * 64 + srow;
      gl_lds16(B + (size_t)(nBase + row) * K + kt * 32 + sgl,
               &lds[s][1][(j * 256 + t) * 8]);
    }
  };

  stage(0, 0);
  stage(1, 1);

  const int arow0 = (wrow * 64 + l16) * 32;
  const int brow0 = (wcol * 64 + l16) * 32;
  const int gsw = (quad ^ ((l16 >> 1) & 3)) * 8;

  for (int kt = 0; kt < NTILES; ++kt) {
    const int s = kt & 3;
    if (kt + 2 < NTILES) {
      stage((kt + 2) & 3, kt + 2);
      asm volatile("s_waitcnt vmcnt(8)" ::: "memory");
    } else if (kt + 1 < NTILES) {
      asm volatile("s_waitcnt vmcnt(4)" ::: "memory");
    } else {
      asm volatile("s_waitcnt vmcnt(0)" ::: "memory");
    }
    __builtin_amdgcn_s_barrier();

    const unsigned short* As = &lds[s][0][0];
    const unsigned short* Bs = &lds[s][1][0];
    bf16x8 af[4], bq[4];
#pragma unroll
    for (int mi = 0; mi < 4; ++mi)
      af[mi] = *(const bf16x8*)(As + arow0 + mi * 512 + gsw);
#pragma unroll
    for (int ni = 0; ni < 4; ++ni)
      bq[ni] = *(const bf16x8*)(Bs + brow0 + ni * 512 + gsw);
    __builtin_amdgcn_s_setprio(1);
#pragma unroll
    for (int mi = 0; mi < 4; ++mi)
#pragma unroll
      for (int ni = 0; ni < 4; ++ni)
        acc[mi][ni] = __builtin_amdgcn_mfma_f32_16x16x32_bf16(
            af[mi], bq[ni], acc[mi][ni], 0, 0, 0);
    __builtin_amdgcn_s_setprio(0);
  }

#pragma unroll
  for (int mi = 0; mi < 4; ++mi)
#pragma unroll
    for (int r = 0; r < 4; ++r) {
      const int row = mBase + wrow * 64 + mi * 16 + quad * 4 + r;
#pragma unroll
      for (int ni = 0; ni < 4; ++ni) {
        const int col = nBase + wcol * 64 + ni * 16 + l16;
        Cf[(size_t)row * N + col] = acc[mi][ni][r] + bias[col];
      }
    }
}

// --------------------------- adain stats (two-stage) ------------------------
__global__ __launch_bounds__(320) void k_stats1(
    const unsigned short* __restrict__ qb, const unsigned short* __restrict__ kb,
    float* __restrict__ psum, float* __restrict__ psq) {
  const int z = blockIdx.y, which = z >> 2, b = z & 3;
  const unsigned short* src = (which == 0) ? qb : kb;
  const int c = threadIdx.x * 4;
  const size_t base = (size_t)(b * 1024 + blockIdx.x * 32) * 1280 + c;
  float4 s = {0.f, 0.f, 0.f, 0.f}, s2 = {0.f, 0.f, 0.f, 0.f};
#pragma unroll 8
  for (int i = 0; i < 32; ++i) {
    const ushort4 xv = *(const ushort4*)(src + base + (size_t)i * 1280);
    const float x0 = bf2f(xv.x), x1 = bf2f(xv.y), x2 = bf2f(xv.z),
                x3 = bf2f(xv.w);
    s.x += x0; s.y += x1; s.z += x2; s.w += x3;
    s2.x = fmaf(x0, x0, s2.x); s2.y = fmaf(x1, x1, s2.y);
    s2.z = fmaf(x2, x2, s2.z); s2.w = fmaf(x3, x3, s2.w);
  }
  const size_t o = ((size_t)z * 32 + blockIdx.x) * 1280 + c;
  *(float4*)(psum + o) = s;
  *(float4*)(psq + o) = s2;
}

// stats2: reduce partials for ALL 4 batches, emit folded affine coefficients.
// fst layout [(coef*4 + b)*1280 + c]: coef 0=gQ, 1=oQ, 2=gK*S2, 3=oK.
__global__ __launch_bounds__(BDIM) void k_stats2(
    const float* __restrict__ psum, const float* __restrict__ psq,
    float* __restrict__ fst) {
  const int which = blockIdx.y;  // 0=Q, 1=K
  const int c = blockIdx.x * 256 + threadIdx.x;
  float m[4], sd[4];
#pragma unroll
  for (int b = 0; b < 4; ++b) {
    const int z = which * 4 + b;
    float s = 0.f, s2 = 0.f;
#pragma unroll
    for (int j = 0; j < 32; ++j) {
      s += psum[((size_t)z * 32 + j) * 1280 + c];
      s2 += psq[((size_t)z * 32 + j) * 1280 + c];
    }
    const float mean = s * (1.0f / 1024.0f);
    const float var = (s2 - 1024.0f * mean * mean) * (1.0f / 1023.0f);
    m[b] = mean;
    sd[b] = sqrtf(var + 1e-5f);
  }
  const float S2 = 0.125f * 1.44269504088896341f;
#pragma unroll
  for (int b = 0; b < 4; ++b) {
    const int bs = (b < 2) ? 0 : 2;
    const float g = sd[bs] / sd[b];
    const float o = m[bs] - m[b] * g;
    if (which == 0) {
      fst[(0 * 4 + b) * 1280 + c] = g;
      fst[(1 * 4 + b) * 1280 + c] = o;
    } else {
      fst[(2 * 4 + b) * 1280 + c] = g * S2;
      fst[(3 * 4 + b) * 1280 + c] = o;
    }
  }
}

// --------------------------- V transpose only -------------------------------
__global__ __launch_bounds__(BDIM) void k_vt(
    const unsigned short* __restrict__ vb, unsigned short* __restrict__ vt) {
  __shared__ unsigned short tile[64][65];
  const int tb = blockIdx.x;            // [0,1280)
  const int b = tb / 320;
  const int r2 = tb - b * 320;
  const int c0 = (r2 / 16) * 64;
  const int s0 = (r2 & 15) * 64;
  const int t = threadIdx.x;
  const int r = t >> 2, seg = (t & 3) * 16;
  const size_t goff = ((size_t)(b * 1024 + s0 + r)) * 1280 + c0 + seg;
  const u16x8 va = *(const u16x8*)(vb + goff);
  const u16x8 vv = *(const u16x8*)(vb + goff + 8);
#pragma unroll
  for (int j = 0; j < 8; j++) {
    tile[r][seg + j] = va[j];
    tile[r][seg + 8 + j] = vv[j];
  }
  __syncthreads();
  u16x8 o0, o1;
#pragma unroll
  for (int j = 0; j < 8; j++) {
    o0[j] = tile[seg + j][r];
    o1[j] = tile[seg + 8 + j][r];
  }
  const size_t ooff = ((size_t)(b * 1280 + c0 + r)) * 1024 + s0 + seg;
  *(u16x8*)(vt + ooff) = o0;
  *(u16x8*)(vt + ooff + 8) = o1;
}

// --------------------------- flash attention --------------------------------
// grid (8,20,6) = 960 blocks x 16 K-tiles. zs: 0=b0 direct, 1/2=b1 self/style
// (Opart slices 0/1), 3=b2 direct, 4/5=b3 self/style (slices 2/3).
// Direct blocks normalize by lsum in-kernel and write attnb.
__global__ __launch_bounds__(BDIM, 4) void k_attn(
    const unsigned short* __restrict__ qb, const unsigned short* __restrict__ kb,
    const float* __restrict__ fst, const unsigned short* __restrict__ vt,
    unsigned short* __restrict__ Opart, float* __restrict__ Lpart,
    unsigned short* __restrict__ attnb) {
  const int S = 1024;
  const int L = blockIdx.x + 8 * (blockIdx.y + 20 * blockIdx.z);
  const int qt = (L >> 3) & 7;
  const int hz = (L & 7) + ((L >> 6) << 3);  // 0..119
  const int h = hz % 20;
  const int zs = hz / 20;                    // 0..5
  int b, ktBeg;
  bool direct;
  if (zs == 0)      { b = 0; ktBeg = 0;  direct = true;  }
  else if (zs == 1) { b = 1; ktBeg = 0;  direct = false; }
  else if (zs == 2) { b = 1; ktBeg = 16; direct = false; }
  else if (zs == 3) { b = 2; ktBeg = 0;  direct = true;  }
  else if (zs == 4) { b = 3; ktBeg = 0;  direct = false; }
  else              { b = 3; ktBeg = 16; direct = false; }
  const int t = threadIdx.x, w = t >> 6, lane = t & 63;
  const int quad = lane >> 4, l16 = lane & 15;
  const int bstyle = (b < 2) ? 0 : 2;
  const int qrow = qt * 128 + w * 32;
  const bool style = (ktBeg >= 16);

  __shared__ unsigned short Ks[2][2][64 * 32];  // [buf][dim-half] 16 KB
  __shared__ unsigned short Vs[2][64 * 32];     // [key-half]       8 KB
  __shared__ unsigned short Plds[4][32][64];    // XOR-swizzled    16 KB

  const float S2 = 0.125f * 1.44269504088896341f;

  const int krow = t >> 2;
  const int kseg = ((t & 3) ^ ((t >> 3) & 3)) * 8;  // T2 pre-swizzled source
  const int sw = l16 & 14;
  const int qsw = (quad ^ ((l16 >> 1) & 3)) * 8;    // T2 read-side XOR

  auto stageK = [&](int buf, int kt) {
    const int bs = (kt < 16) ? b : bstyle;
    const int sk = (kt & 15) * 64;
    const unsigned short* kg =
        kb + (size_t)(bs * S + sk + krow) * 1280 + h * 64 + kseg;
    gl_lds16(kg, Ks[buf][0] + t * 8);
    gl_lds16(kg + 32, Ks[buf][1] + t * 8);
  };
  auto stageV = [&](int kt) {
    const int bs = (kt < 16) ? b : bstyle;
    const int sk = (kt & 15) * 64;
    const unsigned short* vg =
        vt + (size_t)(bs * 1280 + h * 64 + krow) * S + sk + kseg;
    gl_lds16(vg, Vs[0] + t * 8);
    gl_lds16(vg + 32, Vs[1] + t * 8);
  };

  // issue first K-tile staging BEFORE the prologue: HBM latency hides under
  // the prologue's fma chain.
  stageK(0, ktBeg);

  // ---- prologue: folded affine on Q, bias scalar (no divisions) ----
  bf16x8 aq[2][2];
  float biasv[2];
  {
    const int bk = style ? bstyle : b;  // K-coef batch (style: {S2, 0})
    float rq[2] = {0.f, 0.f};
#pragma unroll
    for (int hf = 0; hf < 2; ++hf) {
      const int cc = h * 64 + quad * 8 + hf * 32;
      float gq[8], oq[8], gs[8], ok[8];
      *(float4*)(gq)     = *(const float4*)(fst + (0 * 4 + b) * 1280 + cc);
      *(float4*)(gq + 4) = *(const float4*)(fst + (0 * 4 + b) * 1280 + cc + 4);
      *(float4*)(oq)     = *(const float4*)(fst + (1 * 4 + b) * 1280 + cc);
      *(float4*)(oq + 4) = *(const float4*)(fst + (1 * 4 + b) * 1280 + cc + 4);
      *(float4*)(gs)     = *(const float4*)(fst + (2 * 4 + bk) * 1280 + cc);
      *(float4*)(gs + 4) = *(const float4*)(fst + (2 * 4 + bk) * 1280 + cc + 4);
      *(float4*)(ok)     = *(const float4*)(fst + (3 * 4 + bk) * 1280 + cc);
      *(float4*)(ok + 4) = *(const float4*)(fst + (3 * 4 + bk) * 1280 + cc + 4);
#pragma unroll
      for (int g = 0; g < 2; ++g) {
        const size_t qoff =
            ((size_t)(b * S + qrow + g * 16 + l16)) * 1280 + cc;
        const bf16x8 qv = *(const bf16x8*)(qb + qoff);
        bf16x8 av;
#pragma unroll
        for (int j = 0; j < 8; ++j) {
          const float qn = fmaf((float)qv[j], gq[j], oq[j]);
          rq[g] = fmaf(qn, ok[j], rq[g]);
          av[j] = (__bf16)(qn * gs[j]);
        }
        aq[g][hf] = av;
      }
    }
    const float shift = style ? 1.0f : 0.0f;
#pragma unroll
    for (int g = 0; g < 2; ++g) {
      float r = rq[g] * S2;
      r += __shfl_xor(r, 16, 64);  // sum over the 4 quads of one query row
      r += __shfl_xor(r, 32, 64);
      biasv[g] = shift + r;        // direct blocks: rq==0 exactly -> bias=0
    }
  }

  bf16x8 ones;
#pragma unroll
  for (int i = 0; i < 8; ++i) ones[i] = (__bf16)1.0f;

  f32x4 o[2][4], lsum[2];
#pragma unroll
  for (int g = 0; g < 2; ++g) {
    lsum[g] = (f32x4){0.f, 0.f, 0.f, 0.f};
#pragma unroll
    for (int i = 0; i < 4; i++) o[g][i] = (f32x4){0.f, 0.f, 0.f, 0.f};
  }

  for (int i = 0; i < 16; ++i) {
    const int kt = ktBeg + i;
    const int buf = i & 1;
    asm volatile("s_waitcnt vmcnt(0)" ::: "memory");
    __builtin_amdgcn_s_barrier();
    stageV(kt);
    if (i + 1 < 16) stageK(buf ^ 1, kt + 1);

    // S^T: D[m=key (nt*16+quad*4+r)][n=query l16]
    f32x4 z2[2][4];
#pragma unroll
    for (int nt = 0; nt < 4; ++nt) {
      const bf16x8 bk0 =
          *(const bf16x8*)(Ks[buf][0] + (nt * 16 + l16) * 32 + qsw);
      const bf16x8 bk1 =
          *(const bf16x8*)(Ks[buf][1] + (nt * 16 + l16) * 32 + qsw);
#pragma unroll
      for (int g = 0; g < 2; ++g) {
        f32x4 zz = (f32x4){0.f, 0.f, 0.f, 0.f};
        zz = __builtin_amdgcn_mfma_f32_16x16x32_bf16(bk0, aq[g][0], zz, 0, 0, 0);
        zz = __builtin_amdgcn_mfma_f32_16x16x32_bf16(bk1, aq[g][1], zz, 0, 0, 0);
        z2[g][nt] = zz;
      }
    }

    // exp2 (bias folded), pack -> swizzled b64 write
#pragma unroll
    for (int g = 0; g < 2; ++g) {
      const float bg = biasv[g];
#pragma unroll
      for (int nt = 0; nt < 4; ++nt) {
        const float e0 = exp2f(z2[g][nt][0] + bg);
        const float e1 = exp2f(z2[g][nt][1] + bg);
        const float e2 = exp2f(z2[g][nt][2] + bg);
        const float e3 = exp2f(z2[g][nt][3] + bg);
        uint2 pk;
        pk.x = pack_bf2(e0, e1);
        pk.y = pack_bf2(e2, e3);
        const int phys = (nt * 4 + quad) ^ sw;
        *(uint2*)(&Plds[w][g * 16 + l16][phys * 4]) = pk;
      }
    }

    if (i + 1 < 16)
      asm volatile("s_waitcnt vmcnt(2)" ::: "memory");
    else
      asm volatile("s_waitcnt vmcnt(0)" ::: "memory");
    __builtin_amdgcn_s_barrier();

    // lsum += P*1 ; O += P*V^T
#pragma unroll
    for (int g = 0; g < 2; ++g) {
      const int a0 = (2 * quad) ^ sw;
      const int a1 = (2 * quad + 8) ^ sw;
      const bf16x8 pa0 = *(const bf16x8*)(&Plds[w][g * 16 + l16][a0 * 4]);
      const bf16x8 pa1 = *(const bf16x8*)(&Plds[w][g * 16 + l16][a1 * 4]);
      lsum[g] = __builtin_amdgcn_mfma_f32_16x16x32_bf16(pa0, ones, lsum[g], 0, 0, 0);
      lsum[g] = __builtin_amdgcn_mfma_f32_16x16x32_bf16(pa1, ones, lsum[g], 0, 0, 0);
#pragma unroll
      for (int dt = 0; dt < 4; ++dt) {
        const bf16x8 vb0 =
            *(const bf16x8*)(Vs[0] + (dt * 16 + l16) * 32 + qsw);
        const bf16x8 vb1 =
            *(const bf16x8*)(Vs[1] + (dt * 16 + l16) * 32 + qsw);
        o[g][dt] =
            __builtin_amdgcn_mfma_f32_16x16x32_bf16(pa0, vb0, o[g][dt], 0, 0, 0);
        o[g][dt] =
            __builtin_amdgcn_mfma_f32_16x16x32_bf16(pa1, vb1, o[g][dt], 0, 0, 0);
      }
    }
  }

  if (direct) {
    // normalize in-kernel, write final attn rows for b0/b2
    unsigned short* ab =
        attnb + ((size_t)(b * S + qrow)) * 1280 + h * 64;
#pragma unroll
    for (int g = 0; g < 2; ++g)
#pragma unroll
      for (int r = 0; r < 4; ++r) {
        const float rl = 1.0f / lsum[g][r];
        const int ro = (g * 16 + quad * 4 + r) * 1280;
#pragma unroll
        for (int dt = 0; dt < 4; ++dt)
          ab[ro + dt * 16 + l16] = f2bf(o[g][dt][r] * rl);
      }
  } else {
    const int slice = (zs < 3) ? (zs - 1) : (zs - 2);  // 0..3
    if (l16 == 0) {
#pragma unroll
      for (int g = 0; g < 2; ++g)
#pragma unroll
        for (int r = 0; r < 4; ++r)
          Lpart[((size_t)slice * 20 + h) * 1024 + qrow + g * 16 + quad * 4 +
                r] = lsum[g][r];
    }
    unsigned short* Op = Opart + (size_t)slice * 1310720;
#pragma unroll
    for (int g = 0; g < 2; ++g)
#pragma unroll
      for (int dt = 0; dt < 4; ++dt)
#pragma unroll
        for (int r = 0; r < 4; ++r)
          Op[(size_t)(qrow + g * 16 + quad * 4 + r) * 1280 + h * 64 + dt * 16 +
             l16] = f2bf(o[g][dt][r]);
  }
}

// --------------------------- combine b1/b3 partials -------------------------
// 2048 rows (b1, b3) x 1280 c / 8 per thread -> 1280 blocks.
__global__ __launch_bounds__(BDIM) void k_combine(
    const unsigned short* __restrict__ Opart, const float* __restrict__ Lpart,
    unsigned short* __restrict__ attnb) {
  const int idx = blockIdx.x * BDIM + threadIdx.x;  // [0, 327680)
  const int row = idx / 160;                        // 0..2047
  const int c = (idx - row * 160) * 8;
  const int bb = row >> 10;                         // 0 -> b1, 1 -> b3
  const int q = row & 1023;
  const int h = c >> 6;
  const int s0 = bb * 2;                            // slices {0,1} or {2,3}
  float L = 0.f;
  float acc[8] = {0.f, 0.f, 0.f, 0.f, 0.f, 0.f, 0.f, 0.f};
#pragma unroll
  for (int s = 0; s < 2; ++s) {
    const int z = s0 + s;
    L += Lpart[((size_t)z * 20 + h) * 1024 + q];
    const u16x8 v =
        *(const u16x8*)(Opart + (size_t)z * 1310720 + (size_t)q * 1280 + c);
#pragma unroll
    for (int j = 0; j < 8; ++j) acc[j] += bf2f(v[j]);
  }
  const float rl = 1.0f / L;
  const int orow = (bb * 2 + 1) * 1024 + q;         // batch 1 or 3
  u16x8 o8;
#pragma unroll
  for (int j = 0; j < 8; ++j) o8[j] = f2bf(acc[j] * rl);
  *(u16x8*)(attnb + (size_t)orow * 1280 + c) = o8;
}

// ---------------------------------------------------------------------------
extern "C" void kernel_launch(void* const* d_in, const int* in_sizes, int n_in,
                              void* d_out, int out_size, void* d_ws,
                              size_t ws_size, hipStream_t stream) {
  const float* X = (const float*)d_in[0];
  const float* Wq = (const float*)d_in[1];
  const float* Wk = (const float*)d_in[2];
  const float* Wv = (const float*)d_in[3];
  const float* Wo = (const float*)d_in[4];
  const float* bo = (const float*)d_in[5];
  float* out = (float*)d_out;

  char* ws = (char*)d_ws;
  size_t off = 0;
  auto alloc = [&](size_t bytes) {
    char* p = ws + off;
    off += (bytes + 255) & ~(size_t)255;
    return p;
  };
  unsigned short* Wcat = (unsigned short*)alloc(3840ull * 1280 * 2);
  unsigned short* Xbf = (unsigned short*)alloc(4096ull * 1280 * 2);
  unsigned short* qbb = (unsigned short*)alloc(4096ull * 1280 * 2);
  unsigned short* kbb = (unsigned short*)alloc(4096ull * 1280 * 2);
  unsigned short* vbb = (unsigned short*)alloc(4096ull * 1280 * 2);
  unsigned short* Wobf = (unsigned short*)alloc(1280ull * 1280 * 2);
  float* fstats = (float*)alloc(4ull * 4 * 1280 * 4);
  unsigned short* qnb = (unsigned short*)alloc(4096ull * 1280 * 2);
  unsigned short* knb = (unsigned short*)alloc(4096ull * 1280 * 2);
  unsigned short* vtb = (unsigned short*)alloc(4096ull * 1280 * 2);
  unsigned short* attnb = (unsigned short*)alloc(4096ull * 1280 * 2);
  (void)qnb;
  (void)knb;

  unsigned short* Opart = Xbf;  // 4 slices x 1024 x 1280 bf16 (Xbf dead)
  float* Lpart = (float*)Wcat;                        // 4 x 20 x 1024 fp32
  float* psum = (float*)attnb;                        // 8 x 32 x 1280 fp32
  float* psq = (float*)(attnb + 4096ull * 1280 / 2);  // second half

  k_convert_all<<<11520, BDIM, 0, stream>>>(X, Wq, Wk, Wv, Wo, Xbf, Wcat, Wobf);
  k_gemm_bf16<<<240, 512, 0, stream>>>(Xbf, Wcat, qbb, kbb, vbb, 4096, 3840,
                                       1280);
  k_stats1<<<dim3(32, 8), 320, 0, stream>>>(qbb, kbb, psum, psq);
  k_stats2<<<dim3(5, 2), BDIM, 0, stream>>>(psum, psq, fstats);
  k_vt<<<1280, BDIM, 0, stream>>>(vbb, vtb);
  k_attn<<<dim3(8, 20, 6), BDIM, 0, stream>>>(qbb, kbb, fstats, vtb, Opart,
                                              Lpart, attnb);
  k_combine<<<1280, BDIM, 0, stream>>>(Opart, Lpart, attnb);
  k_gemm_out<<<320, BDIM, 0, stream>>>(attnb, Wobf, out, bo, 4096, 1280, 1280);
}